// Round 3
// baseline (183.193 us; speedup 1.0000x reference)
//
#include <hip/hip_runtime.h>
#include <hip/hip_bf16.h>

// SSL-HSIC on MI355X, round 3: LDS-A (XOR-swizzled) + occupancy + lean epilogue.
// N=8192, D=128, B=4096, M=2, GAMMA=3, SIGMA=1.
// exp2-folding: xb = bf16(x*sqrt(log2e)), hp = log2e*||x||^2/2, so
// K = exp2(min(dot' - hp_i - hp_j, 0)) with the -(hp_i+hp_j) folded into the
// MFMA C-initializer. Epilogue per K: min, v_exp, fma, add.

using bf16   = __bf16;
using bf16x8 = __attribute__((ext_vector_type(8))) __bf16;
using f32x4  = __attribute__((ext_vector_type(4))) float;

#define N_ROWS 8192
#define SQRT_LOG2E 1.2011224087864498f
#define LOG2E      1.4426950408889634f

// ---------------------------------------------------------------- prep ----
__global__ __launch_bounds__(256) void prep_kernel(
    const float* __restrict__ feat, unsigned short* __restrict__ xb,
    float* __restrict__ hp) {
  const int w = threadIdx.x >> 6, lane = threadIdx.x & 63;
  const int row = blockIdx.x * 4 + w;  // one wave per row
  const float2 x2 = ((const float2*)feat)[row * 64 + lane];
  float ss = x2.x * x2.x + x2.y * x2.y;
#pragma unroll
  for (int m = 1; m < 64; m <<= 1) ss += __shfl_xor(ss, m);
  if (lane == 0) hp[row] = 0.5f * LOG2E * ss;
  const unsigned int ux = __float_as_uint(x2.x * SQRT_LOG2E);
  const unsigned int uy = __float_as_uint(x2.y * SQRT_LOG2E);
  ushort2 o;
  o.x = (unsigned short)((ux + 0x7FFFu + ((ux >> 16) & 1u)) >> 16);
  o.y = (unsigned short)((uy + 0x7FFFu + ((uy >> 16) & 1u)) >> 16);
  ((ushort2*)xb)[row * 64 + lane] = o;
}

// ---------------------------------------------------------------- gram ----
// grid (16 col-chunks, 64 row-blocks); block = 4 waves 2x2 over 128x128,
// 4 column tiles per block. A-tile staged once in LDS (XOR swizzle
// byte^((row&7)<<4) -> conflict-free ds_read_b128). B streamed from L2.
__global__ __launch_bounds__(256, 4) void gram_kernel(
    const bf16* __restrict__ xb, const float* __restrict__ hp,
    float* __restrict__ rpart, float* __restrict__ bscal) {
  const int bjc = blockIdx.x, bi = blockIdx.y;
  const int tid = threadIdx.x, lane = tid & 63, w = tid >> 6;
  const int wr = w >> 1, wc = w & 1;
  const int l15 = lane & 15, l4 = lane >> 4;

  __shared__ char  lds_a[32768];   // 128 rows x 256B, swizzled
  __shared__ float lds_ha[128];
  __shared__ float rbuf[128];
  __shared__ float sS[4], sD[4], sP[4];

  // ---- cooperative fill: 2048 16B chunks, 8 per thread ----
  {
    const int rowbase = bi * 128;
#pragma unroll
    for (int i = 0; i < 8; ++i) {
      const int c = tid + i * 256;
      const int row = c >> 4;
      const int byteoff = (c & 15) << 4;
      const bf16x8 vv =
          *(const bf16x8*)(xb + (rowbase + row) * 128 + (byteoff >> 1));
      const int sw = ((row << 8) | byteoff) ^ ((row & 7) << 4);
      *(bf16x8*)(lds_a + sw) = vv;
    }
    if (tid < 128) {
      lds_ha[tid] = hp[rowbase + tid];
      rbuf[tid] = 0.f;
    }
  }
  __syncthreads();

  float rsum[4][4] = {};
  float s2a = 0.f, s2b = 0.f, pdiag = 0.f, ppos = 0.f;

  for (int t = 0; t < 4; ++t) {
    const int bj = bjc * 4 + t;
    const int brow0 = bj * 128 + wc * 64;

    float hb[4];
#pragma unroll
    for (int fc = 0; fc < 4; ++fc) hb[fc] = hp[brow0 + fc * 16 + l15];

    // C-init = -(hp_i + hp_j): kills two subs per K in the epilogue
    f32x4 acc[4][4];
#pragma unroll
    for (int fr = 0; fr < 4; ++fr) {
      const f32x4 hav = *(const f32x4*)(&lds_ha[wr * 64 + fr * 16 + l4 * 4]);
#pragma unroll
      for (int fc = 0; fc < 4; ++fc)
#pragma unroll
        for (int e = 0; e < 4; ++e) acc[fr][fc][e] = -hav[e] - hb[fc];
    }

#pragma unroll
    for (int ks = 0; ks < 4; ++ks) {
      bf16x8 b[4];
#pragma unroll
      for (int f = 0; f < 4; ++f)
        b[f] = *(const bf16x8*)(xb + (brow0 + f * 16 + l15) * 128 + ks * 32 +
                                l4 * 8);
#pragma unroll
      for (int fr = 0; fr < 4; ++fr) {
        const int arow = wr * 64 + fr * 16 + l15;
        const int byte = (arow << 8) + ks * 64 + (l4 << 4);
        const bf16x8 a = *(const bf16x8*)(lds_a + (byte ^ ((arow & 7) << 4)));
#pragma unroll
        for (int fc = 0; fc < 4; ++fc)
          acc[fr][fc] = __builtin_amdgcn_mfma_f32_16x16x32_bf16(
              a, b[fc], acc[fr][fc], 0, 0, 0);
      }
    }

    const int dt = bj - bi;
    const bool isd = (dt == 0);
    const bool isp = (dt == 32) | (dt == -32);

#pragma unroll
    for (int fr = 0; fr < 4; ++fr) {
#pragma unroll
      for (int fc = 0; fc < 4; ++fc) {
#pragma unroll
        for (int e = 0; e < 4; ++e) {
          const float me = fminf(acc[fr][fc][e], 0.f);
          const float K = exp2f(me);
          if (fc & 1) s2b = fmaf(K, K, s2b); else s2a = fmaf(K, K, s2a);
          rsum[fr][e] += K;
          if (isd | isp) {
            const int rr = wr * 64 + fr * 16 + l4 * 4 + e;
            const int cc = wc * 64 + fc * 16 + l15;
            const float hit = (rr == cc) ? K : 0.f;
            if (isd) pdiag += hit; else ppos += hit;
          }
        }
      }
    }
  }

  // ---- block-level reduction (LDS only) ----
#pragma unroll
  for (int fr = 0; fr < 4; ++fr) {
#pragma unroll
    for (int e = 0; e < 4; ++e) {
      float r = rsum[fr][e];
      r += __shfl_xor(r, 1);
      r += __shfl_xor(r, 2);
      r += __shfl_xor(r, 4);
      r += __shfl_xor(r, 8);
      if (l15 == 0) atomicAdd(&rbuf[wr * 64 + fr * 16 + l4 * 4 + e], r);
    }
  }
  float s2 = s2a + s2b;
#pragma unroll
  for (int m = 1; m < 64; m <<= 1) {
    s2 += __shfl_xor(s2, m);
    pdiag += __shfl_xor(pdiag, m);
    ppos += __shfl_xor(ppos, m);
  }
  if (lane == 0) { sS[w] = s2; sD[w] = pdiag; sP[w] = ppos; }
  __syncthreads();

  const int slot = bi * 16 + bjc;
  if (tid < 128) rpart[slot * 128 + tid] = rbuf[tid];
  if (tid == 0) {
    bscal[slot * 3 + 0] = sS[0] + sS[1] + sS[2] + sS[3];
    bscal[slot * 3 + 1] = sD[0] + sD[1] + sD[2] + sD[3];
    bscal[slot * 3 + 2] = sP[0] + sP[1] + sP[2] + sP[3];
  }
}

// --------------------------------------------------------------- final ----
__global__ __launch_bounds__(256) void final_kernel(
    const float* __restrict__ rpart, const float* __restrict__ bscal,
    float* __restrict__ out) {
  const int tid = threadIdx.x, lane = tid & 63, w = tid >> 6;
  double t = 0.0, v2 = 0.0, s2 = 0.0, dg = 0.0, ps = 0.0;
  for (int i = tid; i < N_ROWS; i += 256) {
    const int rb = i >> 7, r = i & 127;
    float s = 0.f;
#pragma unroll
    for (int c = 0; c < 16; ++c) s += rpart[(rb * 16 + c) * 128 + r];
    const double x = (double)s;
    t += x;
    v2 += x * x;
  }
  for (int i = tid; i < 1024; i += 256) {
    s2 += (double)bscal[i * 3 + 0];
    dg += (double)bscal[i * 3 + 1];
    ps += (double)bscal[i * 3 + 2];
  }
#pragma unroll
  for (int m = 1; m < 64; m <<= 1) {
    t += __shfl_xor(t, m);
    v2 += __shfl_xor(v2, m);
    s2 += __shfl_xor(s2, m);
    dg += __shfl_xor(dg, m);
    ps += __shfl_xor(ps, m);
  }
  __shared__ double sh[5][4];
  if (lane == 0) {
    sh[0][w] = t; sh[1][w] = v2; sh[2][w] = s2; sh[3][w] = dg; sh[4][w] = ps;
  }
  __syncthreads();
  if (tid == 0) {
    const double T  = sh[0][0] + sh[0][1] + sh[0][2] + sh[0][3];
    const double V2 = sh[1][0] + sh[1][1] + sh[1][2] + sh[1][3];
    const double S2 = sh[2][0] + sh[2][1] + sh[2][2] + sh[2][3];
    const double DG = sh[3][0] + sh[3][1] + sh[3][2] + sh[3][3];
    const double PS = sh[4][0] + sh[4][1] + sh[4][2] + sh[4][3];
    const double Nd = 8192.0, Bd = 4096.0;
    const double hzz = (S2 - (2.0 / Nd) * V2 + (T * T) / (Nd * Nd)) / (Nd * Nd);
    const double neg = (T - DG) - PS;
    const double t1 = PS / 8192.0;       // B*M*(M-1)
    const double t2 = neg / 67108864.0;  // B^2*M^2
    const double hzy = (Bd / (Bd - 1.0)) * (t1 - t2 - 1.0);
    out[0] = (float)(-hzy + 3.0 * sqrt(fmax(hzz, 0.0)));
  }
}

// -------------------------------------------------------------- launch ----
extern "C" void kernel_launch(void* const* d_in, const int* in_sizes, int n_in,
                              void* d_out, int out_size, void* d_ws,
                              size_t ws_size, hipStream_t stream) {
  (void)in_sizes; (void)n_in; (void)out_size; (void)ws_size;
  const float* feat = (const float*)d_in[0];
  char* ws = (char*)d_ws;
  // ws: xb 2MB | hp 32KB | rpart 512KB | bscal 12KB  (~2.55 MB)
  unsigned short* xb = (unsigned short*)ws;
  float* hp    = (float*)(ws + 2097152);
  float* rpart = (float*)(ws + 2097152 + 32768);
  float* bscal = (float*)(ws + 2097152 + 32768 + 524288);
  float* out = (float*)d_out;

  prep_kernel<<<2048, 256, 0, stream>>>(feat, xb, hp);
  gram_kernel<<<dim3(16, 64), 256, 0, stream>>>((const bf16*)xb, hp, rpart,
                                                bscal);
  final_kernel<<<1, 256, 0, stream>>>(rpart, bscal, out);
}

// Round 4
// 137.929 us; speedup vs baseline: 1.3282x; 1.3282x over previous
//
#include <hip/hip_runtime.h>
#include <hip/hip_bf16.h>

// SSL-HSIC on MI355X, round 4.
// N=8192, D=128, B=4096, M=2, GAMMA=3, SIGMA=1.
// Rows are L2-normalized by the reference => ||x_i||^2 == 1 exactly, so
// K = exp(min(dot-1,0)) = exp2(min(log2e*dot - log2e, 0)).
// log2e is folded into the A-side bf16 conversion; C-init = -log2e.
// Round-3 lesson: launch_bounds(256,4) forced acc spill -> 380MB scratch
// traffic, HBM-bound. Now (256,2), no prep kernel (fp32 converted inline),
// B-fragment software pipeline one k-step ahead.

using bf16   = __bf16;
using bf16x8 = __attribute__((ext_vector_type(8))) __bf16;
using f32x4  = __attribute__((ext_vector_type(4))) float;

#define N_ROWS 8192
#define LOG2E 1.4426950408889634f

__device__ inline bf16x8 cvt8s(const float4 a, const float4 b, const float s) {
  bf16x8 r;
  r[0] = (__bf16)(a.x * s); r[1] = (__bf16)(a.y * s);
  r[2] = (__bf16)(a.z * s); r[3] = (__bf16)(a.w * s);
  r[4] = (__bf16)(b.x * s); r[5] = (__bf16)(b.y * s);
  r[6] = (__bf16)(b.z * s); r[7] = (__bf16)(b.w * s);
  return r;
}

// ---------------------------------------------------------------- gram ----
// grid (8 col-chunks, 64 row-blocks); block = 4 waves 2x2 over 128x128 tile,
// 8 column tiles per block. A staged once in swizzled LDS (scaled by log2e);
// B streamed fp32->bf16 in registers, pipelined one k-step ahead.
__global__ __launch_bounds__(256, 2) void gram_kernel(
    const float* __restrict__ feat, float* __restrict__ rpart,
    float* __restrict__ bscal) {
  const int bjc = blockIdx.x, bi = blockIdx.y;
  const int tid = threadIdx.x, lane = tid & 63, w = tid >> 6;
  const int wr = w >> 1, wc = w & 1;
  const int l15 = lane & 15, l4 = lane >> 4;

  __shared__ char  lds_a[32768];   // 128 rows x 256B bf16, XOR-swizzled
  __shared__ float rbuf[128];
  __shared__ float sS[4], sD[4], sP[4];

  // ---- stage A: fp32 -> bf16(*log2e) -> swizzled LDS ----
  {
    const int rowbase = bi * 128;
#pragma unroll
    for (int i = 0; i < 8; ++i) {
      const int c = tid + i * 256;       // 2048 chunks of 8 elems
      const int row = c >> 4, seg = c & 15;
      const float4* p = (const float4*)(feat + (rowbase + row) * 128 + seg * 8);
      const float4 x0 = p[0], x1 = p[1];
      const int sw = ((row << 8) | (seg << 4)) ^ ((row & 7) << 4);
      *(bf16x8*)(lds_a + sw) = cvt8s(x0, x1, LOG2E);
    }
    if (tid < 128) rbuf[tid] = 0.f;
  }
  __syncthreads();

  float rsum[4][4] = {};
  float s2a = 0.f, s2b = 0.f, pdiag = 0.f, ppos = 0.f;

  // B pipeline registers: fp32 for k-step in flight
  float4 bn[4][2];
  {
    const int brow0 = (bjc * 8) * 128 + wc * 64;
#pragma unroll
    for (int f = 0; f < 4; ++f) {
      const float* p = feat + (brow0 + f * 16 + l15) * 128 + l4 * 8;
      bn[f][0] = *(const float4*)p;
      bn[f][1] = *(const float4*)(p + 4);
    }
  }

  for (int t = 0; t < 8; ++t) {
    const int bj = bjc * 8 + t;
    const int brow0 = bj * 128 + wc * 64;

    f32x4 acc[4][4];
#pragma unroll
    for (int fr = 0; fr < 4; ++fr)
#pragma unroll
      for (int fc = 0; fc < 4; ++fc)
#pragma unroll
        for (int e = 0; e < 4; ++e) acc[fr][fc][e] = -LOG2E;

#pragma unroll
    for (int ks = 0; ks < 4; ++ks) {
      bf16x8 bb[4];
#pragma unroll
      for (int f = 0; f < 4; ++f) bb[f] = cvt8s(bn[f][0], bn[f][1], 1.0f);

      // prefetch next k-step (or next tile's ks=0)
      if (ks < 3 || t < 7) {
        const int nks = (ks < 3) ? ks + 1 : 0;
        const int nbrow0 = (ks < 3) ? brow0 : brow0 + 128;
#pragma unroll
        for (int f = 0; f < 4; ++f) {
          const float* p =
              feat + (nbrow0 + f * 16 + l15) * 128 + nks * 32 + l4 * 8;
          bn[f][0] = *(const float4*)p;
          bn[f][1] = *(const float4*)(p + 4);
        }
      }

#pragma unroll
      for (int fr = 0; fr < 4; ++fr) {
        const int arow = wr * 64 + fr * 16 + l15;
        const int byte = (arow << 8) + ks * 64 + (l4 << 4);
        const bf16x8 a = *(const bf16x8*)(lds_a + (byte ^ ((arow & 7) << 4)));
#pragma unroll
        for (int fc = 0; fc < 4; ++fc)
          acc[fr][fc] = __builtin_amdgcn_mfma_f32_16x16x32_bf16(
              a, bb[fc], acc[fr][fc], 0, 0, 0);
      }
    }

    const int dt = bj - bi;
    const bool isd = (dt == 0);
    const bool isp = (dt == 32) | (dt == -32);

#pragma unroll
    for (int fr = 0; fr < 4; ++fr) {
#pragma unroll
      for (int fc = 0; fc < 4; ++fc) {
#pragma unroll
        for (int e = 0; e < 4; ++e) {
          const float me = fminf(acc[fr][fc][e], 0.f);
          const float K = exp2f(me);
          if (fc & 1) s2b = fmaf(K, K, s2b); else s2a = fmaf(K, K, s2a);
          rsum[fr][e] += K;
          if (isd | isp) {
            const int rr = wr * 64 + fr * 16 + l4 * 4 + e;
            const int cc = wc * 64 + fc * 16 + l15;
            const float hit = (rr == cc) ? K : 0.f;
            if (isd) pdiag += hit; else ppos += hit;
          }
        }
      }
    }
  }

  // ---- block-level reductions (LDS only) ----
#pragma unroll
  for (int fr = 0; fr < 4; ++fr) {
#pragma unroll
    for (int e = 0; e < 4; ++e) {
      float r = rsum[fr][e];
      r += __shfl_xor(r, 1);
      r += __shfl_xor(r, 2);
      r += __shfl_xor(r, 4);
      r += __shfl_xor(r, 8);
      if (l15 == 0) atomicAdd(&rbuf[wr * 64 + fr * 16 + l4 * 4 + e], r);
    }
  }
  float s2 = s2a + s2b;
#pragma unroll
  for (int m = 1; m < 64; m <<= 1) {
    s2 += __shfl_xor(s2, m);
    pdiag += __shfl_xor(pdiag, m);
    ppos += __shfl_xor(ppos, m);
  }
  if (lane == 0) { sS[w] = s2; sD[w] = pdiag; sP[w] = ppos; }
  __syncthreads();

  const int slot = bi * 8 + bjc;
  if (tid < 128) rpart[slot * 128 + tid] = rbuf[tid];
  if (tid == 0) {
    bscal[slot * 3 + 0] = sS[0] + sS[1] + sS[2] + sS[3];
    bscal[slot * 3 + 1] = sD[0] + sD[1] + sD[2] + sD[3];
    bscal[slot * 3 + 2] = sP[0] + sP[1] + sP[2] + sP[3];
  }
}

// --------------------------------------------------------------- final ----
__global__ __launch_bounds__(256) void final_kernel(
    const float* __restrict__ rpart, const float* __restrict__ bscal,
    float* __restrict__ out) {
  const int tid = threadIdx.x, lane = tid & 63, w = tid >> 6;
  double t = 0.0, v2 = 0.0, s2 = 0.0, dg = 0.0, ps = 0.0;
  for (int i = tid; i < N_ROWS; i += 256) {
    const int rb = i >> 7, r = i & 127;
    float s = 0.f;
#pragma unroll
    for (int c = 0; c < 8; ++c) s += rpart[(rb * 8 + c) * 128 + r];
    const double x = (double)s;
    t += x;
    v2 += x * x;
  }
  for (int i = tid; i < 512; i += 256) {
    s2 += (double)bscal[i * 3 + 0];
    dg += (double)bscal[i * 3 + 1];
    ps += (double)bscal[i * 3 + 2];
  }
#pragma unroll
  for (int m = 1; m < 64; m <<= 1) {
    t += __shfl_xor(t, m);
    v2 += __shfl_xor(v2, m);
    s2 += __shfl_xor(s2, m);
    dg += __shfl_xor(dg, m);
    ps += __shfl_xor(ps, m);
  }
  __shared__ double sh[5][4];
  if (lane == 0) {
    sh[0][w] = t; sh[1][w] = v2; sh[2][w] = s2; sh[3][w] = dg; sh[4][w] = ps;
  }
  __syncthreads();
  if (tid == 0) {
    const double T  = sh[0][0] + sh[0][1] + sh[0][2] + sh[0][3];
    const double V2 = sh[1][0] + sh[1][1] + sh[1][2] + sh[1][3];
    const double S2 = sh[2][0] + sh[2][1] + sh[2][2] + sh[2][3];
    const double DG = sh[3][0] + sh[3][1] + sh[3][2] + sh[3][3];
    const double PS = sh[4][0] + sh[4][1] + sh[4][2] + sh[4][3];
    const double Nd = 8192.0, Bd = 4096.0;
    const double hzz = (S2 - (2.0 / Nd) * V2 + (T * T) / (Nd * Nd)) / (Nd * Nd);
    const double neg = (T - DG) - PS;
    const double t1 = PS / 8192.0;       // B*M*(M-1)
    const double t2 = neg / 67108864.0;  // B^2*M^2
    const double hzy = (Bd / (Bd - 1.0)) * (t1 - t2 - 1.0);
    out[0] = (float)(-hzy + 3.0 * sqrt(fmax(hzz, 0.0)));
  }
}

// -------------------------------------------------------------- launch ----
extern "C" void kernel_launch(void* const* d_in, const int* in_sizes, int n_in,
                              void* d_out, int out_size, void* d_ws,
                              size_t ws_size, hipStream_t stream) {
  (void)in_sizes; (void)n_in; (void)out_size; (void)ws_size;
  const float* feat = (const float*)d_in[0];
  char* ws = (char*)d_ws;
  // ws: rpart 256KB | bscal 6KB
  float* rpart = (float*)ws;
  float* bscal = (float*)(ws + 262144);
  float* out = (float*)d_out;

  gram_kernel<<<dim3(8, 64), 256, 0, stream>>>(feat, rpart, bscal);
  final_kernel<<<1, 256, 0, stream>>>(rpart, bscal, out);
}